// Round 13
// baseline (168.388 us; speedup 1.0000x reference)
//
#include <hip/hip_runtime.h>

typedef __attribute__((ext_vector_type(8))) __bf16 bf16x8;
typedef __attribute__((ext_vector_type(4))) float f32x4;
typedef __attribute__((ext_vector_type(8))) unsigned short u16x8;
typedef __attribute__((ext_vector_type(4))) unsigned short u16x4;

#define DEV __device__ __forceinline__

DEV float bf2f(unsigned short u) {
  unsigned int x = ((unsigned int)u) << 16;
  return __builtin_bit_cast(float, x);
}
DEV unsigned short f2bf(float f) {
  unsigned int u = __builtin_bit_cast(unsigned int, f);
  u = u + 0x7fffu + ((u >> 16) & 1u);
  return (unsigned short)(u >> 16);
}
// HW packed f32->bf16 RNE; D[15:0]=bf16(first arg)
DEV unsigned int cvtpk(float a, float b) {
  unsigned int r;
  asm("v_cvt_pk_bf16_f32 %0, %1, %2" : "=v"(r) : "v"(a), "v"(b));
  return r;
}

DEV void glds16(const void* g, void* l) {
  __builtin_amdgcn_global_load_lds(
      (__attribute__((address_space(1))) void*)g,
      (__attribute__((address_space(3))) void*)l, 16, 0, 0);
}

// ---------------- one-shot prep ----------------
__global__ __launch_bounds__(256) void k_prep(
    const float* __restrict__ x, const float* __restrict__ Wq,
    const float* __restrict__ Wk, const float* __restrict__ Wv,
    const float* __restrict__ Wp, const float* __restrict__ prompt,
    const float* __restrict__ bk, const float* __restrict__ bv,
    unsigned short* __restrict__ xb, unsigned short* __restrict__ wqb,
    unsigned short* __restrict__ wkvb, unsigned short* __restrict__ wpb,
    unsigned short* __restrict__ pb, float* __restrict__ bkv,
    unsigned short* __restrict__ vt2) {
  const int blk = blockIdx.x;
  const int tid = threadIdx.x;
  if (blk < 2048) {
    for (int i = blk * 256 + tid; i < 6291456; i += 524288) {
      float4 v = reinterpret_cast<const float4*>(x)[i];
      u16x4 o;
      o[0] = f2bf(v.x); o[1] = f2bf(v.y); o[2] = f2bf(v.z); o[3] = f2bf(v.w);
      reinterpret_cast<u16x4*>(xb)[i] = o;
    }
  } else if (blk < 4352) {
    const int w = (blk - 2048) / 576;  // 0:Wq 1:Wk 2:Wv 3:Wp
    const int i = (blk - 2048 - w * 576) * 256 + tid;
    const float* src = (w == 0) ? Wq : (w == 1) ? Wk : (w == 2) ? Wv : Wp;
    unsigned short* dst =
        (w == 0) ? wqb : (w == 1) ? wkvb : (w == 2) ? (wkvb + 589824) : wpb;
    float4 v = reinterpret_cast<const float4*>(src)[i];
    u16x4 o;
    o[0] = f2bf(v.x); o[1] = f2bf(v.y); o[2] = f2bf(v.z); o[3] = f2bf(v.w);
    reinterpret_cast<u16x4*>(dst)[i] = o;
  } else if (blk < 5120) {
    const int i4 = (blk - 4352) * 256 + tid;  // < 196608
    const int e = i4 * 4;
    const int b = e / 98304;
    const int rem = e - b * 98304;
    const int s = rem / 768;
    const int d = rem - s * 768;
    u16x4 o;
    if (s < 77) {
      float4 v = *reinterpret_cast<const float4*>(&prompt[((long)b * 77 + s) * 768 + d]);
      o[0] = f2bf(v.x); o[1] = f2bf(v.y); o[2] = f2bf(v.z); o[3] = f2bf(v.w);
    } else {
      o[0] = 0; o[1] = 0; o[2] = 0; o[3] = 0;
    }
    reinterpret_cast<u16x4*>(pb)[i4] = o;
  } else if (blk < 5126) {
    const int i = (blk - 5120) * 256 + tid;
    if (i < 1536) bkv[i] = (i < 768) ? bk[i] : bv[i - 768];
  } else {
    const int i = (blk - 5126) * 256 + tid;  // < 79872 u16x8 units
    u16x8 z = {};
    reinterpret_cast<u16x8*>(vt2)[i] = z;
  }
}

// ======== merged KV projection (blocks 0..95, FIRST) + Q-projection GEMM (BK=128) ========
// KV path: BK=64 as before; K rows -> kvt flat quirk; V rows -> vt2 pre-transposed quirk.
// Q path: BK=128 (6 K-iters, halves the HBM-latency drains). LDS chunked layout:
//   chunk(u,kh) = rows u*8..u*8+7 x cols kh*64..+63 stored 512 elems contiguous;
//   per-64-half XOR swizzle (source slot (lane&7)^(lane>>3); read col c64^((fr&7)*8)).
__global__ __launch_bounds__(256, 2) void k_qkv(
    const unsigned short* __restrict__ WQ, const unsigned short* __restrict__ XB,
    unsigned short* __restrict__ QT, const float* __restrict__ BQ,
    const unsigned short* __restrict__ WKV, const unsigned short* __restrict__ PB,
    unsigned short* __restrict__ KV, unsigned short* __restrict__ VT2,
    const float* __restrict__ BKV) {
  __shared__ alignas(16) unsigned short S[32768];  // 64 KB

  const int tid = threadIdx.x;
  const int wave = tid >> 6;
  const int lane = tid & 63;
  const int wm = (wave >> 1) * 64;
  const int wn = (wave & 1) * 64;
  const int fr = lane & 15;
  const int fk = (lane >> 4) * 8;
  const int srow = lane >> 3;
  const int r0 = (lane >> 4) * 4;  // C/D: col=lane&15, row=(lane>>4)*4+reg

  if (blockIdx.x < 96) {
    // ---------------- KV path (dispatches first, overlaps Q rounds) ----------------
    unsigned short* const As = S;
    unsigned short* const Bs = S + 8192;
    const int idx = blockIdx.x;  // 0..95
    const int bz = idx / 12;
    const int tm = (idx - bz * 12) * 128;
    const unsigned short* Bb = PB + (long)bz * 98304;
    const int scol = (lane & 7) * 8;

    f32x4 acc[4][4] = {};
    for (int k0 = 0; k0 < 768; k0 += 64) {
      __syncthreads();
#pragma unroll
      for (int i = 0; i < 4; ++i) {
        const int chunk = i * 4 + wave;
        glds16(WKV + (long)(tm + chunk * 8 + srow) * 768 + (k0 + scol), &As[chunk * 512]);
      }
#pragma unroll
      for (int i = 0; i < 4; ++i) {
        const int chunk = i * 4 + wave;
        glds16(Bb + (long)(chunk * 8 + srow) * 768 + (k0 + scol), &Bs[chunk * 512]);
      }
      __syncthreads();
#pragma unroll
      for (int ks = 0; ks < 2; ++ks) {
        bf16x8 af[4], bf[4];
#pragma unroll
        for (int mi = 0; mi < 4; ++mi)
          af[mi] = *reinterpret_cast<const bf16x8*>(&As[(wm + mi * 16 + fr) * 64 + ks * 32 + fk]);
#pragma unroll
        for (int ni = 0; ni < 4; ++ni)
          bf[ni] = *reinterpret_cast<const bf16x8*>(&Bs[(wn + ni * 16 + fr) * 64 + ks * 32 + fk]);
#pragma unroll
        for (int mi = 0; mi < 4; ++mi)
#pragma unroll
          for (int ni = 0; ni < 4; ++ni)
            acc[mi][ni] =
                __builtin_amdgcn_mfma_f32_16x16x32_bf16(af[mi], bf[ni], acc[mi][ni], 0, 0, 0);
      }
    }
#pragma unroll
    for (int mi = 0; mi < 4; ++mi) {
#pragma unroll
      for (int ni = 0; ni < 4; ++ni) {
        const int col = wn + ni * 16 + fr;
        if (col < 77) {
#pragma unroll
          for (int r = 0; r < 4; ++r) {
            const int row = tm + wm + mi * 16 + r0 + r;
            const unsigned short v = f2bf(acc[mi][ni][r] + BKV[row]);
            if (tm < 768) {
              KV[(long)bz * 59136 + (long)row * 77 + col] = v;
            } else {
              const int p = (row - 768) * 77 + col;
              const int snew = p / 768;
              const int c0 = p - snew * 768;
              VT2[(long)bz * 79872 + (long)c0 * 104 + snew] = v;
            }
          }
        }
      }
    }
    return;
  }

  // ---------------- Q path, BK=128 ----------------
  const int bid = blockIdx.x - 96;  // 0..1535; 96%8==0 preserves XCD mapping
  const int l = (bid & 7) * 192 + (bid >> 3);
  const int tm = (l % 6) * 128;
  const int tn = (l / 6) * 128;
  const int srcx = ((lane & 7) ^ srow) * 8;  // pre-swizzled source col (per 64-half)
  const int rx = (fr & 7) * 8;               // ds_read XOR
  unsigned short* const Aq = S;              // 16384 elems (32 chunks x 512)
  unsigned short* const Bq = S + 16384;

  f32x4 acc[4][4] = {};
  for (int k0 = 0; k0 < 768; k0 += 128) {
    __syncthreads();
#pragma unroll
    for (int i = 0; i < 8; ++i) {
      const int c = i * 4 + wave;            // 0..31
      const int u = c >> 1;
      const int kh = (c & 1) * 64;
      glds16(WQ + (long)(tm + u * 8 + srow) * 768 + (k0 + kh + srcx), &Aq[c * 512]);
    }
#pragma unroll
    for (int i = 0; i < 8; ++i) {
      const int c = i * 4 + wave;
      const int u = c >> 1;
      const int kh = (c & 1) * 64;
      glds16(XB + (long)(tn + u * 8 + srow) * 768 + (k0 + kh + srcx), &Bq[c * 512]);
    }
    __syncthreads();
#pragma unroll
    for (int ks = 0; ks < 4; ++ks) {
      const int col = ks * 32 + fk;                       // 0..120
      const int cbase = ((col >> 6) << 9) + ((col & 63) ^ rx);  // kh*512 + swz c64
      bf16x8 af[4], bf[4];
#pragma unroll
      for (int mi = 0; mi < 4; ++mi) {
        const int row = wm + mi * 16 + fr;
        af[mi] = *reinterpret_cast<const bf16x8*>(
            &Aq[(row >> 3) * 1024 + (row & 7) * 64 + cbase]);
      }
#pragma unroll
      for (int ni = 0; ni < 4; ++ni) {
        const int row = wn + ni * 16 + fr;
        bf[ni] = *reinterpret_cast<const bf16x8*>(
            &Bq[(row >> 3) * 1024 + (row & 7) * 64 + cbase]);
      }
#pragma unroll
      for (int mi = 0; mi < 4; ++mi)
#pragma unroll
        for (int ni = 0; ni < 4; ++ni)
          acc[mi][ni] =
              __builtin_amdgcn_mfma_f32_16x16x32_bf16(af[mi], bf[ni], acc[mi][ni], 0, 0, 0);
    }
  }

  // quirk epilogue: bias + cvt_pk into LDS [cm][ct] (stride 136), coalesced stores
  __syncthreads();
#pragma unroll
  for (int mi = 0; mi < 4; ++mi) {
    const int cmb = wm + mi * 16 + r0;
#pragma unroll
    for (int ni = 0; ni < 4; ++ni) {
      const int ct = wn + ni * 16 + fr;
      const unsigned int p01 =
          cvtpk(acc[mi][ni][0] + BQ[tm + cmb], acc[mi][ni][1] + BQ[tm + cmb + 1]);
      const unsigned int p23 =
          cvtpk(acc[mi][ni][2] + BQ[tm + cmb + 2], acc[mi][ni][3] + BQ[tm + cmb + 3]);
      S[(cmb + 0) * 136 + ct] = (unsigned short)p01;
      S[(cmb + 1) * 136 + ct] = (unsigned short)(p01 >> 16);
      S[(cmb + 2) * 136 + ct] = (unsigned short)p23;
      S[(cmb + 3) * 136 + ct] = (unsigned short)(p23 >> 16);
    }
  }
  __syncthreads();
  const int b_ = tn >> 12;
  const int toff = tn & 4095;
  const int cm = tid >> 1;
  const int t8 = (tid & 1) * 64;
  const long gb = (long)b_ * 3145728 + (long)(tm + cm) * 4096 + toff + t8;
#pragma unroll
  for (int j = 0; j < 8; ++j)
    *reinterpret_cast<u16x8*>(&QT[gb + j * 8]) =
        *reinterpret_cast<const u16x8*>(&S[cm * 136 + t8 + j * 8]);
}

// ======== 128x128 out-GEMM, BK=128, XCD-chunked 1D grid + T2 swizzle (f32 out) ========
__global__ __launch_bounds__(256, 2) void k_gout(const unsigned short* __restrict__ A,
                                                 const unsigned short* __restrict__ B,
                                                 float* __restrict__ out,
                                                 const float* __restrict__ bias) {
  __shared__ alignas(16) unsigned short S[32768];  // 64 KB
  unsigned short* const As = S;
  unsigned short* const Bs = S + 16384;

  const int tid = threadIdx.x;
  const int wave = tid >> 6;
  const int lane = tid & 63;
  const int l = (blockIdx.x & 7) * 192 + (blockIdx.x >> 3);
  const int tm = (l / 6) * 128;
  const int tn = (l % 6) * 128;
  const int wm = (wave >> 1) * 64;
  const int wn = (wave & 1) * 64;
  const int fr = lane & 15;
  const int fk = (lane >> 4) * 8;
  const int srow = lane >> 3;
  const int srcx = ((lane & 7) ^ srow) * 8;
  const int rx = (fr & 7) * 8;

  f32x4 acc[4][4] = {};

  for (int k0 = 0; k0 < 768; k0 += 128) {
    __syncthreads();
#pragma unroll
    for (int i = 0; i < 8; ++i) {
      const int c = i * 4 + wave;
      const int u = c >> 1;
      const int kh = (c & 1) * 64;
      glds16(A + (long)(tm + u * 8 + srow) * 768 + (k0 + kh + srcx), &As[c * 512]);
    }
#pragma unroll
    for (int i = 0; i < 8; ++i) {
      const int c = i * 4 + wave;
      const int u = c >> 1;
      const int kh = (c & 1) * 64;
      glds16(B + (long)(tn + u * 8 + srow) * 768 + (k0 + kh + srcx), &Bs[c * 512]);
    }
    __syncthreads();
#pragma unroll
    for (int ks = 0; ks < 4; ++ks) {
      const int col = ks * 32 + fk;
      const int cbase = ((col >> 6) << 9) + ((col & 63) ^ rx);
      bf16x8 af[4], bf[4];
#pragma unroll
      for (int mi = 0; mi < 4; ++mi) {
        const int row = wm + mi * 16 + fr;
        af[mi] = *reinterpret_cast<const bf16x8*>(
            &As[(row >> 3) * 1024 + (row & 7) * 64 + cbase]);
      }
#pragma unroll
      for (int ni = 0; ni < 4; ++ni) {
        const int row = wn + ni * 16 + fr;
        bf[ni] = *reinterpret_cast<const bf16x8*>(
            &Bs[(row >> 3) * 1024 + (row & 7) * 64 + cbase]);
      }
#pragma unroll
      for (int mi = 0; mi < 4; ++mi)
#pragma unroll
        for (int ni = 0; ni < 4; ++ni)
          acc[mi][ni] =
              __builtin_amdgcn_mfma_f32_16x16x32_bf16(af[mi], bf[ni], acc[mi][ni], 0, 0, 0);
    }
  }

  const int r0 = (lane >> 4) * 4;
#pragma unroll
  for (int mi = 0; mi < 4; ++mi) {
#pragma unroll
    for (int ni = 0; ni < 4; ++ni) {
      const int col = tn + wn + ni * 16 + fr;
      const float bv = bias[col];
#pragma unroll
      for (int r = 0; r < 4; ++r) {
        const long g = tm + wm + mi * 16 + r0 + r;
        out[g * 768 + col] = acc[mi][ni][r] + bv;
      }
    }
  }
}

// ---------------- MFMA fused cross-attention (+ setprio around MFMA clusters) ----------------
__global__ __launch_bounds__(256, 4) void k_attn(const unsigned short* __restrict__ QT,
                                                 const unsigned short* __restrict__ KVT,
                                                 const unsigned short* __restrict__ VT2,
                                                 unsigned short* __restrict__ Y) {
  __shared__ alignas(16) unsigned short Plds[128 * 104];  // P, then O-bounce
  __shared__ alignas(16) unsigned short Vt[64 * 104];

  const int b = blockIdx.z;
  const int h = blockIdx.y;
  const int tid = threadIdx.x;
  const int wave = tid >> 6;
  const int lane = tid & 63;
  const int fr = lane & 15;
  const int fg = lane >> 4;

  const unsigned short* vsrc = VT2 + (long)b * 79872 + h * 6656;
#pragma unroll
  for (int r = 0; r < 4; ++r) {
    const int chunk = r * 256 + tid;
    if (chunk < 832) glds16(vsrc + chunk * 8, &Vt[chunk * 8]);
  }

  {
    const int row = wave * 32 + (lane >> 1);
    u16x8 z = {};
    *reinterpret_cast<u16x8*>(&Plds[row * 104 + 80 + (lane & 1) * 8]) = z;
  }

  const int t0 = blockIdx.x * 128 + wave * 32;
  const long qb = (long)b * 3145728 + h * 64;
  const long kflat = (long)b * 59136 + h * 64;

  bf16x8 qa[2][2];
#pragma unroll
  for (int m = 0; m < 2; ++m)
#pragma unroll
    for (int ks = 0; ks < 2; ++ks)
      qa[m][ks] = *reinterpret_cast<const bf16x8*>(
          &QT[qb + (long)(t0 + m * 16 + fr) * 768 + ks * 32 + fg * 8]);

  bf16x8 kb[5][2];
#pragma unroll
  for (int n = 0; n < 5; ++n)
#pragma unroll
    for (int ks = 0; ks < 2; ++ks)
      kb[n][ks] = *reinterpret_cast<const bf16x8*>(
          &KVT[kflat + (long)(n * 16 + fr) * 768 + ks * 32 + fg * 8]);

  f32x4 s_[2][5] = {};
  __builtin_amdgcn_s_setprio(1);
#pragma unroll
  for (int ks = 0; ks < 2; ++ks)
#pragma unroll
    for (int m = 0; m < 2; ++m)
#pragma unroll
      for (int n = 0; n < 5; ++n)
        s_[m][n] = __builtin_amdgcn_mfma_f32_16x16x32_bf16(qa[m][ks], kb[n][ks], s_[m][n], 0, 0, 0);
  __builtin_amdgcn_s_setprio(0);

  const float scale = 0.036084391824351615f;  // 1/sqrt(768) (quirk: d_prompt)
  f32x4 rl[2];
#pragma unroll
  for (int m = 0; m < 2; ++m) {
#pragma unroll
    for (int n = 0; n < 5; ++n) {
      const int key = n * 16 + fr;
#pragma unroll
      for (int r = 0; r < 4; ++r)
        s_[m][n][r] = (key < 77) ? __expf(s_[m][n][r] * scale) : 0.f;
    }
    f32x4 t = s_[m][0] + s_[m][1] + s_[m][2] + s_[m][3] + s_[m][4];
#pragma unroll
    for (int w = 1; w < 16; w <<= 1) {
      f32x4 u;
#pragma unroll
      for (int r = 0; r < 4; ++r) u[r] = __shfl_xor(t[r], w);
      t += u;
    }
    rl[m][0] = 1.f / t[0]; rl[m][1] = 1.f / t[1];
    rl[m][2] = 1.f / t[2]; rl[m][3] = 1.f / t[3];
  }

#pragma unroll
  for (int m = 0; m < 2; ++m)
#pragma unroll
    for (int n = 0; n < 5; ++n) {
      const unsigned int p01 = cvtpk(s_[m][n][0], s_[m][n][1]);
      const unsigned int p23 = cvtpk(s_[m][n][2], s_[m][n][3]);
      const int base = wave * 32 + m * 16 + fg * 4;
      const int col = n * 16 + fr;
      Plds[(base + 0) * 104 + col] = (unsigned short)p01;
      Plds[(base + 1) * 104 + col] = (unsigned short)(p01 >> 16);
      Plds[(base + 2) * 104 + col] = (unsigned short)p23;
      Plds[(base + 3) * 104 + col] = (unsigned short)(p23 >> 16);
    }

  __syncthreads();  // drains glds16 V-stage + P writes

  f32x4 o[2][4] = {};
  __builtin_amdgcn_s_setprio(1);
#pragma unroll
  for (int ks = 0; ks < 3; ++ks) {
    bf16x8 pa[2], vb[4];
#pragma unroll
    for (int m = 0; m < 2; ++m)
      pa[m] = *reinterpret_cast<const bf16x8*>(
          &Plds[(wave * 32 + m * 16 + fr) * 104 + ks * 32 + fg * 8]);
#pragma unroll
    for (int n = 0; n < 4; ++n)
      vb[n] = *reinterpret_cast<const bf16x8*>(&Vt[(n * 16 + fr) * 104 + ks * 32 + fg * 8]);
#pragma unroll
    for (int m = 0; m < 2; ++m)
#pragma unroll
      for (int n = 0; n < 4; ++n)
        o[m][n] = __builtin_amdgcn_mfma_f32_16x16x32_bf16(pa[m], vb[n], o[m][n], 0, 0, 0);
  }
  __builtin_amdgcn_s_setprio(0);

#pragma unroll
  for (int m = 0; m < 2; ++m)
#pragma unroll
    for (int n = 0; n < 4; ++n) {
      const unsigned int p01 = cvtpk(o[m][n][0] * rl[m][0], o[m][n][1] * rl[m][1]);
      const unsigned int p23 = cvtpk(o[m][n][2] * rl[m][2], o[m][n][3] * rl[m][3]);
      const int base = wave * 32 + m * 16 + fg * 4;
      const int col = n * 16 + fr;
      Plds[(base + 0) * 104 + col] = (unsigned short)p01;
      Plds[(base + 1) * 104 + col] = (unsigned short)(p01 >> 16);
      Plds[(base + 2) * 104 + col] = (unsigned short)p23;
      Plds[(base + 3) * 104 + col] = (unsigned short)(p23 >> 16);
    }
#pragma unroll
  for (int j = 0; j < 4; ++j) {
    const int chunk = j * 64 + lane;
    const int row = chunk >> 3;
    const int d8 = (chunk & 7) * 8;
    *reinterpret_cast<u16x8*>(&Y[qb + (long)(t0 + row) * 768 + d8]) =
        *reinterpret_cast<const u16x8*>(&Plds[(wave * 32 + row) * 104 + d8]);
  }
}

// ---------------- launch ----------------
extern "C" void kernel_launch(void* const* d_in, const int* in_sizes, int n_in,
                              void* d_out, int out_size, void* d_ws, size_t ws_size,
                              hipStream_t stream) {
  const float* x      = (const float*)d_in[0];
  const float* prompt = (const float*)d_in[1];
  const float* Wq     = (const float*)d_in[2];
  const float* bq     = (const float*)d_in[3];
  const float* Wk     = (const float*)d_in[4];
  const float* bk     = (const float*)d_in[5];
  const float* Wv     = (const float*)d_in[6];
  const float* bv     = (const float*)d_in[7];
  const float* Wp     = (const float*)d_in[8];
  const float* bp     = (const float*)d_in[9];
  float* out = (float*)d_out;

  if (ws_size < 109185024u) return;
  char* ws = (char*)d_ws;
  unsigned short* xb   = (unsigned short*)(ws + 0);           // 50,331,648 B
  unsigned short* y    = xb;                                  // alias (xb dead after Q-GEMM)
  unsigned short* qt   = (unsigned short*)(ws + 50331648L);
  unsigned short* wqb  = (unsigned short*)(ws + 100663296L);
  unsigned short* wpb  = (unsigned short*)(ws + 101842944L);
  unsigned short* wkvb = (unsigned short*)(ws + 103022592L);
  unsigned short* pb   = (unsigned short*)(ws + 105381888L);
  unsigned short* kvt  = (unsigned short*)(ws + 106954752L);  // 946,176 B (K only)
  unsigned short* vt2  = (unsigned short*)(ws + 107900928L);  // 1,277,952 B (V^T quirk)
  float*          bkv  = (float*)(ws + 109178880L);           // 6,144 B

  k_prep<<<5438, 256, 0, stream>>>(x, Wq, Wk, Wv, Wp, prompt, bk, bv,
                                   xb, wqb, wkvb, wpb, pb, bkv, vt2);

  // merged: KV projection (96 blocks, FIRST) + Q projection (1536 blocks, BK=128)
  k_qkv<<<1632, 256, 0, stream>>>(wqb, xb, qt, bq, wkvb, pb, kvt, vt2, bkv);

  k_attn<<<dim3(32, 12, 8), 256, 0, stream>>>(qt, kvt, vt2, y);

  // out: A=y flat (32768,768), B=Wp (768,768); f32 out, bias per col; BK=128
  k_gout<<<1536, 256, 0, stream>>>(y, wpb, out, bp);
}

// Round 14
// 166.090 us; speedup vs baseline: 1.0138x; 1.0138x over previous
//
#include <hip/hip_runtime.h>

typedef __attribute__((ext_vector_type(8))) __bf16 bf16x8;
typedef __attribute__((ext_vector_type(4))) float f32x4;
typedef __attribute__((ext_vector_type(8))) unsigned short u16x8;
typedef __attribute__((ext_vector_type(4))) unsigned short u16x4;

#define DEV __device__ __forceinline__

DEV float bf2f(unsigned short u) {
  unsigned int x = ((unsigned int)u) << 16;
  return __builtin_bit_cast(float, x);
}
DEV unsigned short f2bf(float f) {
  unsigned int u = __builtin_bit_cast(unsigned int, f);
  u = u + 0x7fffu + ((u >> 16) & 1u);
  return (unsigned short)(u >> 16);
}
// HW packed f32->bf16 RNE; D[15:0]=bf16(first arg)
DEV unsigned int cvtpk(float a, float b) {
  unsigned int r;
  asm("v_cvt_pk_bf16_f32 %0, %1, %2" : "=v"(r) : "v"(a), "v"(b));
  return r;
}

DEV void glds16(const void* g, void* l) {
  __builtin_amdgcn_global_load_lds(
      (__attribute__((address_space(1))) void*)g,
      (__attribute__((address_space(3))) void*)l, 16, 0, 0);
}

// ---------------- one-shot prep ----------------
// [0,2048): x cvt; [2048,4352): weight cvts; [4352,5120): prompt pad;
// [5120,5126): bkv concat; [5126,5438): vt2 zero-fill.
__global__ __launch_bounds__(256) void k_prep(
    const float* __restrict__ x, const float* __restrict__ Wq,
    const float* __restrict__ Wk, const float* __restrict__ Wv,
    const float* __restrict__ Wp, const float* __restrict__ prompt,
    const float* __restrict__ bk, const float* __restrict__ bv,
    unsigned short* __restrict__ xb, unsigned short* __restrict__ wqb,
    unsigned short* __restrict__ wkvb, unsigned short* __restrict__ wpb,
    unsigned short* __restrict__ pb, float* __restrict__ bkv,
    unsigned short* __restrict__ vt2) {
  const int blk = blockIdx.x;
  const int tid = threadIdx.x;
  if (blk < 2048) {
    for (int i = blk * 256 + tid; i < 6291456; i += 524288) {
      float4 v = reinterpret_cast<const float4*>(x)[i];
      u16x4 o;
      o[0] = f2bf(v.x); o[1] = f2bf(v.y); o[2] = f2bf(v.z); o[3] = f2bf(v.w);
      reinterpret_cast<u16x4*>(xb)[i] = o;
    }
  } else if (blk < 4352) {
    const int w = (blk - 2048) / 576;  // 0:Wq 1:Wk 2:Wv 3:Wp
    const int i = (blk - 2048 - w * 576) * 256 + tid;
    const float* src = (w == 0) ? Wq : (w == 1) ? Wk : (w == 2) ? Wv : Wp;
    unsigned short* dst =
        (w == 0) ? wqb : (w == 1) ? wkvb : (w == 2) ? (wkvb + 589824) : wpb;
    float4 v = reinterpret_cast<const float4*>(src)[i];
    u16x4 o;
    o[0] = f2bf(v.x); o[1] = f2bf(v.y); o[2] = f2bf(v.z); o[3] = f2bf(v.w);
    reinterpret_cast<u16x4*>(dst)[i] = o;
  } else if (blk < 5120) {
    const int i4 = (blk - 4352) * 256 + tid;  // < 196608
    const int e = i4 * 4;
    const int b = e / 98304;
    const int rem = e - b * 98304;
    const int s = rem / 768;
    const int d = rem - s * 768;
    u16x4 o;
    if (s < 77) {
      float4 v = *reinterpret_cast<const float4*>(&prompt[((long)b * 77 + s) * 768 + d]);
      o[0] = f2bf(v.x); o[1] = f2bf(v.y); o[2] = f2bf(v.z); o[3] = f2bf(v.w);
    } else {
      o[0] = 0; o[1] = 0; o[2] = 0; o[3] = 0;
    }
    reinterpret_cast<u16x4*>(pb)[i4] = o;
  } else if (blk < 5126) {
    const int i = (blk - 5120) * 256 + tid;
    if (i < 1536) bkv[i] = (i < 768) ? bk[i] : bv[i - 768];
  } else {
    const int i = (blk - 5126) * 256 + tid;  // < 79872 u16x8 units
    u16x8 z = {};
    reinterpret_cast<u16x8*>(vt2)[i] = z;
  }
}

// ======== merged KV projection (blocks 0..95, FIRST) + Q-projection GEMM (BK=64) ========
// KV path: A=[Wk;Wv](1536,768), B=pb[bz](128,768); K rows -> kvt flat quirk;
//   V rows -> vt2 pre-transposed quirk (stride 104). Runs first to overlap Q rounds
//   (r12 lesson: tail placement cost ~10us; KV-first = free).
// Q path (blocks 96..1631; 96%8==0 keeps XCD-chunk alignment):
//   A=Wq(768,768) tm=(l%6)*128 + T2 swizzle; B=xb bf16 flat(32768,768) tn=(l/6)*128;
//   quirk bf16 store qt[b*3145728+(tm+cm)*4096+t] via LDS transpose, coalesced.
__global__ __launch_bounds__(256, 2) void k_qkv(
    const unsigned short* __restrict__ WQ, const unsigned short* __restrict__ XB,
    unsigned short* __restrict__ QT, const float* __restrict__ BQ,
    const unsigned short* __restrict__ WKV, const unsigned short* __restrict__ PB,
    unsigned short* __restrict__ KV, unsigned short* __restrict__ VT2,
    const float* __restrict__ BKV) {
  __shared__ alignas(16) unsigned short S[17408];
  unsigned short* const As = S;
  unsigned short* const Bs = S + 8192;

  const int tid = threadIdx.x;
  const int wave = tid >> 6;
  const int lane = tid & 63;
  const int wm = (wave >> 1) * 64;
  const int wn = (wave & 1) * 64;
  const int fr = lane & 15;
  const int fk = (lane >> 4) * 8;
  const int srow = lane >> 3;
  const int r0 = (lane >> 4) * 4;  // C/D: col=lane&15, row=(lane>>4)*4+reg

  if (blockIdx.x < 96) {
    // ---------------- KV path (dispatches first, overlaps Q rounds) ----------------
    const int idx = blockIdx.x;  // 0..95
    const int bz = idx / 12;
    const int tm = (idx - bz * 12) * 128;
    const unsigned short* Bb = PB + (long)bz * 98304;
    const int scol = (lane & 7) * 8;

    f32x4 acc[4][4] = {};
    for (int k0 = 0; k0 < 768; k0 += 64) {
      __syncthreads();
#pragma unroll
      for (int i = 0; i < 4; ++i) {
        const int chunk = i * 4 + wave;
        glds16(WKV + (long)(tm + chunk * 8 + srow) * 768 + (k0 + scol), &As[chunk * 512]);
      }
#pragma unroll
      for (int i = 0; i < 4; ++i) {
        const int chunk = i * 4 + wave;
        glds16(Bb + (long)(chunk * 8 + srow) * 768 + (k0 + scol), &Bs[chunk * 512]);
      }
      __syncthreads();
#pragma unroll
      for (int ks = 0; ks < 2; ++ks) {
        bf16x8 af[4], bf[4];
#pragma unroll
        for (int mi = 0; mi < 4; ++mi)
          af[mi] = *reinterpret_cast<const bf16x8*>(&As[(wm + mi * 16 + fr) * 64 + ks * 32 + fk]);
#pragma unroll
        for (int ni = 0; ni < 4; ++ni)
          bf[ni] = *reinterpret_cast<const bf16x8*>(&Bs[(wn + ni * 16 + fr) * 64 + ks * 32 + fk]);
#pragma unroll
        for (int mi = 0; mi < 4; ++mi)
#pragma unroll
          for (int ni = 0; ni < 4; ++ni)
            acc[mi][ni] =
                __builtin_amdgcn_mfma_f32_16x16x32_bf16(af[mi], bf[ni], acc[mi][ni], 0, 0, 0);
      }
    }
#pragma unroll
    for (int mi = 0; mi < 4; ++mi) {
#pragma unroll
      for (int ni = 0; ni < 4; ++ni) {
        const int col = wn + ni * 16 + fr;
        if (col < 77) {
#pragma unroll
          for (int r = 0; r < 4; ++r) {
            const int row = tm + wm + mi * 16 + r0 + r;
            const unsigned short v = f2bf(acc[mi][ni][r] + BKV[row]);
            if (tm < 768) {
              KV[(long)bz * 59136 + (long)row * 77 + col] = v;
            } else {
              const int p = (row - 768) * 77 + col;
              const int snew = p / 768;
              const int c0 = p - snew * 768;
              VT2[(long)bz * 79872 + (long)c0 * 104 + snew] = v;
            }
          }
        }
      }
    }
    return;
  }

  // ---------------- Q path (BK=64) ----------------
  const int bid = blockIdx.x - 96;  // 0..1535; 96%8==0 preserves XCD mapping
  const int l = (bid & 7) * 192 + (bid >> 3);
  const int tm = (l % 6) * 128;
  const int tn = (l / 6) * 128;
  const int srcx = ((lane & 7) ^ srow) * 8;  // pre-swizzled source col
  const int rx = (fr & 7) * 8;               // ds_read XOR

  f32x4 acc[4][4] = {};
  for (int k0 = 0; k0 < 768; k0 += 64) {
    __syncthreads();
#pragma unroll
    for (int i = 0; i < 4; ++i) {
      const int chunk = i * 4 + wave;
      glds16(WQ + (long)(tm + chunk * 8 + srow) * 768 + (k0 + srcx), &As[chunk * 512]);
    }
#pragma unroll
    for (int i = 0; i < 4; ++i) {
      const int chunk = i * 4 + wave;
      glds16(XB + (long)(tn + chunk * 8 + srow) * 768 + (k0 + srcx), &Bs[chunk * 512]);
    }
    __syncthreads();
#pragma unroll
    for (int ks = 0; ks < 2; ++ks) {
      bf16x8 af[4], bf[4];
#pragma unroll
      for (int mi = 0; mi < 4; ++mi)
        af[mi] = *reinterpret_cast<const bf16x8*>(
            &As[(wm + mi * 16 + fr) * 64 + ((ks * 32 + fk) ^ rx)]);
#pragma unroll
      for (int ni = 0; ni < 4; ++ni)
        bf[ni] = *reinterpret_cast<const bf16x8*>(
            &Bs[(wn + ni * 16 + fr) * 64 + ((ks * 32 + fk) ^ rx)]);
#pragma unroll
      for (int mi = 0; mi < 4; ++mi)
#pragma unroll
        for (int ni = 0; ni < 4; ++ni)
          acc[mi][ni] =
              __builtin_amdgcn_mfma_f32_16x16x32_bf16(af[mi], bf[ni], acc[mi][ni], 0, 0, 0);
    }
  }

  // quirk epilogue: bias + cvt_pk into LDS [cm][ct] (stride 136), coalesced stores
  __syncthreads();
#pragma unroll
  for (int mi = 0; mi < 4; ++mi) {
    const int cmb = wm + mi * 16 + r0;
#pragma unroll
    for (int ni = 0; ni < 4; ++ni) {
      const int ct = wn + ni * 16 + fr;
      const unsigned int p01 =
          cvtpk(acc[mi][ni][0] + BQ[tm + cmb], acc[mi][ni][1] + BQ[tm + cmb + 1]);
      const unsigned int p23 =
          cvtpk(acc[mi][ni][2] + BQ[tm + cmb + 2], acc[mi][ni][3] + BQ[tm + cmb + 3]);
      S[(cmb + 0) * 136 + ct] = (unsigned short)p01;
      S[(cmb + 1) * 136 + ct] = (unsigned short)(p01 >> 16);
      S[(cmb + 2) * 136 + ct] = (unsigned short)p23;
      S[(cmb + 3) * 136 + ct] = (unsigned short)(p23 >> 16);
    }
  }
  __syncthreads();
  const int b_ = tn >> 12;
  const int toff = tn & 4095;
  const int cm = tid >> 1;
  const int t8 = (tid & 1) * 64;
  const long gb = (long)b_ * 3145728 + (long)(tm + cm) * 4096 + toff + t8;
#pragma unroll
  for (int j = 0; j < 8; ++j)
    *reinterpret_cast<u16x8*>(&QT[gb + j * 8]) =
        *reinterpret_cast<const u16x8*>(&S[cm * 136 + t8 + j * 8]);
}

// ======== 128x128 out-GEMM (BK=64), XCD-chunked 1D grid + T2 swizzle (f32 out) ========
__global__ __launch_bounds__(256, 2) void k_gout(const unsigned short* __restrict__ A,
                                                 const unsigned short* __restrict__ B,
                                                 float* __restrict__ out,
                                                 const float* __restrict__ bias) {
  __shared__ alignas(16) unsigned short S[16384];
  unsigned short* const As = S;
  unsigned short* const Bs = S + 8192;

  const int tid = threadIdx.x;
  const int wave = tid >> 6;
  const int lane = tid & 63;
  const int l = (blockIdx.x & 7) * 192 + (blockIdx.x >> 3);
  const int tm = (l / 6) * 128;
  const int tn = (l % 6) * 128;
  const int wm = (wave >> 1) * 64;
  const int wn = (wave & 1) * 64;
  const int fr = lane & 15;
  const int fk = (lane >> 4) * 8;
  const int srow = lane >> 3;
  const int srcx = ((lane & 7) ^ srow) * 8;
  const int rx = (fr & 7) * 8;

  f32x4 acc[4][4] = {};

  for (int k0 = 0; k0 < 768; k0 += 64) {
    __syncthreads();
#pragma unroll
    for (int i = 0; i < 4; ++i) {
      const int chunk = i * 4 + wave;
      glds16(A + (long)(tm + chunk * 8 + srow) * 768 + (k0 + srcx), &As[chunk * 512]);
    }
#pragma unroll
    for (int i = 0; i < 4; ++i) {
      const int chunk = i * 4 + wave;
      glds16(B + (long)(tn + chunk * 8 + srow) * 768 + (k0 + srcx), &Bs[chunk * 512]);
    }
    __syncthreads();
#pragma unroll
    for (int ks = 0; ks < 2; ++ks) {
      bf16x8 af[4], bf[4];
#pragma unroll
      for (int mi = 0; mi < 4; ++mi)
        af[mi] = *reinterpret_cast<const bf16x8*>(
            &As[(wm + mi * 16 + fr) * 64 + ((ks * 32 + fk) ^ rx)]);
#pragma unroll
      for (int ni = 0; ni < 4; ++ni)
        bf[ni] = *reinterpret_cast<const bf16x8*>(
            &Bs[(wn + ni * 16 + fr) * 64 + ((ks * 32 + fk) ^ rx)]);
#pragma unroll
      for (int mi = 0; mi < 4; ++mi)
#pragma unroll
        for (int ni = 0; ni < 4; ++ni)
          acc[mi][ni] =
              __builtin_amdgcn_mfma_f32_16x16x32_bf16(af[mi], bf[ni], acc[mi][ni], 0, 0, 0);
    }
  }

  const int r0 = (lane >> 4) * 4;
#pragma unroll
  for (int mi = 0; mi < 4; ++mi) {
#pragma unroll
    for (int ni = 0; ni < 4; ++ni) {
      const int col = tn + wn + ni * 16 + fr;
      const float bv = bias[col];
#pragma unroll
      for (int r = 0; r < 4; ++r) {
        const long g = tm + wm + mi * 16 + r0 + r;
        out[g * 768 + col] = acc[mi][ni][r] + bv;
      }
    }
  }
}

// ---------------- MFMA fused cross-attention (setprio around MFMA clusters) ----------------
__global__ __launch_bounds__(256, 4) void k_attn(const unsigned short* __restrict__ QT,
                                                 const unsigned short* __restrict__ KVT,
                                                 const unsigned short* __restrict__ VT2,
                                                 unsigned short* __restrict__ Y) {
  __shared__ alignas(16) unsigned short Plds[128 * 104];  // P, then O-bounce
  __shared__ alignas(16) unsigned short Vt[64 * 104];

  const int b = blockIdx.z;
  const int h = blockIdx.y;
  const int tid = threadIdx.x;
  const int wave = tid >> 6;
  const int lane = tid & 63;
  const int fr = lane & 15;
  const int fg = lane >> 4;

  const unsigned short* vsrc = VT2 + (long)b * 79872 + h * 6656;
#pragma unroll
  for (int r = 0; r < 4; ++r) {
    const int chunk = r * 256 + tid;
    if (chunk < 832) glds16(vsrc + chunk * 8, &Vt[chunk * 8]);
  }

  {
    const int row = wave * 32 + (lane >> 1);
    u16x8 z = {};
    *reinterpret_cast<u16x8*>(&Plds[row * 104 + 80 + (lane & 1) * 8]) = z;
  }

  const int t0 = blockIdx.x * 128 + wave * 32;
  const long qb = (long)b * 3145728 + h * 64;
  const long kflat = (long)b * 59136 + h * 64;

  bf16x8 qa[2][2];
#pragma unroll
  for (int m = 0; m < 2; ++m)
#pragma unroll
    for (int ks = 0; ks < 2; ++ks)
      qa[m][ks] = *reinterpret_cast<const bf16x8*>(
          &QT[qb + (long)(t0 + m * 16 + fr) * 768 + ks * 32 + fg * 8]);

  bf16x8 kb[5][2];
#pragma unroll
  for (int n = 0; n < 5; ++n)
#pragma unroll
    for (int ks = 0; ks < 2; ++ks)
      kb[n][ks] = *reinterpret_cast<const bf16x8*>(
          &KVT[kflat + (long)(n * 16 + fr) * 768 + ks * 32 + fg * 8]);

  f32x4 s_[2][5] = {};
  __builtin_amdgcn_s_setprio(1);
#pragma unroll
  for (int ks = 0; ks < 2; ++ks)
#pragma unroll
    for (int m = 0; m < 2; ++m)
#pragma unroll
      for (int n = 0; n < 5; ++n)
        s_[m][n] = __builtin_amdgcn_mfma_f32_16x16x32_bf16(qa[m][ks], kb[n][ks], s_[m][n], 0, 0, 0);
  __builtin_amdgcn_s_setprio(0);

  const float scale = 0.036084391824351615f;  // 1/sqrt(768) (quirk: d_prompt)
  f32x4 rl[2];
#pragma unroll
  for (int m = 0; m < 2; ++m) {
#pragma unroll
    for (int n = 0; n < 5; ++n) {
      const int key = n * 16 + fr;
#pragma unroll
      for (int r = 0; r < 4; ++r)
        s_[m][n][r] = (key < 77) ? __expf(s_[m][n][r] * scale) : 0.f;
    }
    f32x4 t = s_[m][0] + s_[m][1] + s_[m][2] + s_[m][3] + s_[m][4];
#pragma unroll
    for (int w = 1; w < 16; w <<= 1) {
      f32x4 u;
#pragma unroll
      for (int r = 0; r < 4; ++r) u[r] = __shfl_xor(t[r], w);
      t += u;
    }
    rl[m][0] = 1.f / t[0]; rl[m][1] = 1.f / t[1];
    rl[m][2] = 1.f / t[2]; rl[m][3] = 1.f / t[3];
  }

#pragma unroll
  for (int m = 0; m < 2; ++m)
#pragma unroll
    for (int n = 0; n < 5; ++n) {
      const unsigned int p01 = cvtpk(s_[m][n][0], s_[m][n][1]);
      const unsigned int p23 = cvtpk(s_[m][n][2], s_[m][n][3]);
      const int base = wave * 32 + m * 16 + fg * 4;
      const int col = n * 16 + fr;
      Plds[(base + 0) * 104 + col] = (unsigned short)p01;
      Plds[(base + 1) * 104 + col] = (unsigned short)(p01 >> 16);
      Plds[(base + 2) * 104 + col] = (unsigned short)p23;
      Plds[(base + 3) * 104 + col] = (unsigned short)(p23 >> 16);
    }

  __syncthreads();  // drains glds16 V-stage + P writes

  f32x4 o[2][4] = {};
  __builtin_amdgcn_s_setprio(1);
#pragma unroll
  for (int ks = 0; ks < 3; ++ks) {
    bf16x8 pa[2], vb[4];
#pragma unroll
    for (int m = 0; m < 2; ++m)
      pa[m] = *reinterpret_cast<const bf16x8*>(
          &Plds[(wave * 32 + m * 16 + fr) * 104 + ks * 32 + fg * 8]);
#pragma unroll
    for (int n = 0; n < 4; ++n)
      vb[n] = *reinterpret_cast<const bf16x8*>(&Vt[(n * 16 + fr) * 104 + ks * 32 + fg * 8]);
#pragma unroll
    for (int m = 0; m < 2; ++m)
#pragma unroll
      for (int n = 0; n < 4; ++n)
        o[m][n] = __builtin_amdgcn_mfma_f32_16x16x32_bf16(pa[m], vb[n], o[m][n], 0, 0, 0);
  }
  __builtin_amdgcn_s_setprio(0);

#pragma unroll
  for (int m = 0; m < 2; ++m)
#pragma unroll
    for (int n = 0; n < 4; ++n) {
      const unsigned int p01 = cvtpk(o[m][n][0] * rl[m][0], o[m][n][1] * rl[m][1]);
      const unsigned int p23 = cvtpk(o[m][n][2] * rl[m][2], o[m][n][3] * rl[m][3]);
      const int base = wave * 32 + m * 16 + fg * 4;
      const int col = n * 16 + fr;
      Plds[(base + 0) * 104 + col] = (unsigned short)p01;
      Plds[(base + 1) * 104 + col] = (unsigned short)(p01 >> 16);
      Plds[(base + 2) * 104 + col] = (unsigned short)p23;
      Plds[(base + 3) * 104 + col] = (unsigned short)(p23 >> 16);
    }
#pragma unroll
  for (int j = 0; j < 4; ++j) {
    const int chunk = j * 64 + lane;
    const int row = chunk >> 3;
    const int d8 = (chunk & 7) * 8;
    *reinterpret_cast<u16x8*>(&Y[qb + (long)(t0 + row) * 768 + d8]) =
        *reinterpret_cast<const u16x8*>(&Plds[(wave * 32 + row) * 104 + d8]);
  }
}

// ---------------- launch ----------------
extern "C" void kernel_launch(void* const* d_in, const int* in_sizes, int n_in,
                              void* d_out, int out_size, void* d_ws, size_t ws_size,
                              hipStream_t stream) {
  const float* x      = (const float*)d_in[0];
  const float* prompt = (const float*)d_in[1];
  const float* Wq     = (const float*)d_in[2];
  const float* bq     = (const float*)d_in[3];
  const float* Wk     = (const float*)d_in[4];
  const float* bk     = (const float*)d_in[5];
  const float* Wv     = (const float*)d_in[6];
  const float* bv     = (const float*)d_in[7];
  const float* Wp     = (const float*)d_in[8];
  const float* bp     = (const float*)d_in[9];
  float* out = (float*)d_out;

  if (ws_size < 109185024u) return;
  char* ws = (char*)d_ws;
  unsigned short* xb   = (unsigned short*)(ws + 0);           // 50,331,648 B
  unsigned short* y    = xb;                                  // alias (xb dead after Q-GEMM)
  unsigned short* qt   = (unsigned short*)(ws + 50331648L);
  unsigned short* wqb  = (unsigned short*)(ws + 100663296L);
  unsigned short* wpb  = (unsigned short*)(ws + 101842944L);
  unsigned short* wkvb = (unsigned short*)(ws + 103022592L);
  unsigned short* pb   = (unsigned short*)(ws + 105381888L);
  unsigned short* kvt  = (unsigned short*)(ws + 106954752L);  // 946,176 B (K only)
  unsigned short* vt2  = (unsigned short*)(ws + 107900928L);  // 1,277,952 B (V^T quirk)
  float*          bkv  = (float*)(ws + 109178880L);           // 6,144 B

  k_prep<<<5438, 256, 0, stream>>>(x, Wq, Wk, Wv, Wp, prompt, bk, bv,
                                   xb, wqb, wkvb, wpb, pb, bkv, vt2);

  // merged: KV projection (96 blocks, FIRST) + Q projection (1536 blocks, BK=64)
  k_qkv<<<1632, 256, 0, stream>>>(wqb, xb, qt, bq, wkvb, pb, kvt, vt2, bkv);

  k_attn<<<dim3(32, 12, 8), 256, 0, stream>>>(qt, kvt, vt2, y);

  // out: A=y flat (32768,768), B=Wp (768,768); f32 out, bias per col
  k_gout<<<1536, 256, 0, stream>>>(y, wpb, out, bp);
}

// Round 15
// 162.151 us; speedup vs baseline: 1.0385x; 1.0243x over previous
//
#include <hip/hip_runtime.h>

typedef __attribute__((ext_vector_type(8))) __bf16 bf16x8;
typedef __attribute__((ext_vector_type(4))) float f32x4;
typedef __attribute__((ext_vector_type(8))) unsigned short u16x8;
typedef __attribute__((ext_vector_type(4))) unsigned short u16x4;

#define DEV __device__ __forceinline__

DEV float bf2f(unsigned short u) {
  unsigned int x = ((unsigned int)u) << 16;
  return __builtin_bit_cast(float, x);
}
DEV unsigned short f2bf(float f) {
  unsigned int u = __builtin_bit_cast(unsigned int, f);
  u = u + 0x7fffu + ((u >> 16) & 1u);
  return (unsigned short)(u >> 16);
}
// HW packed f32->bf16 RNE; D[15:0]=bf16(first arg)
DEV unsigned int cvtpk(float a, float b) {
  unsigned int r;
  asm("v_cvt_pk_bf16_f32 %0, %1, %2" : "=v"(r) : "v"(a), "v"(b));
  return r;
}

DEV void glds16(const void* g, void* l) {
  __builtin_amdgcn_global_load_lds(
      (__attribute__((address_space(1))) void*)g,
      (__attribute__((address_space(3))) void*)l, 16, 0, 0);
}

// ---------------- one-shot prep ----------------
// [0,2048): x cvt; [2048,4352): weight cvts; [4352,5120): prompt pad;
// [5120,5126): bkv concat; [5126,5438): vt2 zero-fill.
__global__ __launch_bounds__(256) void k_prep(
    const float* __restrict__ x, const float* __restrict__ Wq,
    const float* __restrict__ Wk, const float* __restrict__ Wv,
    const float* __restrict__ Wp, const float* __restrict__ prompt,
    const float* __restrict__ bk, const float* __restrict__ bv,
    unsigned short* __restrict__ xb, unsigned short* __restrict__ wqb,
    unsigned short* __restrict__ wkvb, unsigned short* __restrict__ wpb,
    unsigned short* __restrict__ pb, float* __restrict__ bkv,
    unsigned short* __restrict__ vt2) {
  const int blk = blockIdx.x;
  const int tid = threadIdx.x;
  if (blk < 2048) {
    for (int i = blk * 256 + tid; i < 6291456; i += 524288) {
      float4 v = reinterpret_cast<const float4*>(x)[i];
      u16x4 o;
      o[0] = f2bf(v.x); o[1] = f2bf(v.y); o[2] = f2bf(v.z); o[3] = f2bf(v.w);
      reinterpret_cast<u16x4*>(xb)[i] = o;
    }
  } else if (blk < 4352) {
    const int w = (blk - 2048) / 576;  // 0:Wq 1:Wk 2:Wv 3:Wp
    const int i = (blk - 2048 - w * 576) * 256 + tid;
    const float* src = (w == 0) ? Wq : (w == 1) ? Wk : (w == 2) ? Wv : Wp;
    unsigned short* dst =
        (w == 0) ? wqb : (w == 1) ? wkvb : (w == 2) ? (wkvb + 589824) : wpb;
    float4 v = reinterpret_cast<const float4*>(src)[i];
    u16x4 o;
    o[0] = f2bf(v.x); o[1] = f2bf(v.y); o[2] = f2bf(v.z); o[3] = f2bf(v.w);
    reinterpret_cast<u16x4*>(dst)[i] = o;
  } else if (blk < 5120) {
    const int i4 = (blk - 4352) * 256 + tid;  // < 196608
    const int e = i4 * 4;
    const int b = e / 98304;
    const int rem = e - b * 98304;
    const int s = rem / 768;
    const int d = rem - s * 768;
    u16x4 o;
    if (s < 77) {
      float4 v = *reinterpret_cast<const float4*>(&prompt[((long)b * 77 + s) * 768 + d]);
      o[0] = f2bf(v.x); o[1] = f2bf(v.y); o[2] = f2bf(v.z); o[3] = f2bf(v.w);
    } else {
      o[0] = 0; o[1] = 0; o[2] = 0; o[3] = 0;
    }
    reinterpret_cast<u16x4*>(pb)[i4] = o;
  } else if (blk < 5126) {
    const int i = (blk - 5120) * 256 + tid;
    if (i < 1536) bkv[i] = (i < 768) ? bk[i] : bv[i - 768];
  } else {
    const int i = (blk - 5126) * 256 + tid;  // < 79872 u16x8 units
    u16x8 z = {};
    reinterpret_cast<u16x8*>(vt2)[i] = z;
  }
}

// ======== merged KV projection (blocks 0..95, FIRST) + Q-projection GEMM (BK=64) ========
// __launch_bounds__(256,4): force total regs <= 128/wave (64 AGPR acc + <=64 VGPR) to
// cross the m69 register-quantum cliff: 140 regs -> 2 waves/SIMD; <=128 -> 4 waves/SIMD.
// KV path: A=[Wk;Wv](1536,768), B=pb[bz](128,768); K rows -> kvt flat quirk;
//   V rows -> vt2 pre-transposed quirk (stride 104). Runs first to overlap Q rounds.
// Q path (blocks 96..1631; 96%8==0 keeps XCD-chunk alignment):
//   A=Wq(768,768) tm=(l%6)*128 + T2 swizzle; B=xb bf16 flat(32768,768) tn=(l/6)*128;
//   quirk bf16 store qt[b*3145728+(tm+cm)*4096+t] via LDS transpose, coalesced.
__global__ __launch_bounds__(256, 4) void k_qkv(
    const unsigned short* __restrict__ WQ, const unsigned short* __restrict__ XB,
    unsigned short* __restrict__ QT, const float* __restrict__ BQ,
    const unsigned short* __restrict__ WKV, const unsigned short* __restrict__ PB,
    unsigned short* __restrict__ KV, unsigned short* __restrict__ VT2,
    const float* __restrict__ BKV) {
  __shared__ alignas(16) unsigned short S[17408];
  unsigned short* const As = S;
  unsigned short* const Bs = S + 8192;

  const int tid = threadIdx.x;
  const int wave = tid >> 6;
  const int lane = tid & 63;
  const int wm = (wave >> 1) * 64;
  const int wn = (wave & 1) * 64;
  const int fr = lane & 15;
  const int fk = (lane >> 4) * 8;
  const int srow = lane >> 3;
  const int r0 = (lane >> 4) * 4;  // C/D: col=lane&15, row=(lane>>4)*4+reg

  if (blockIdx.x < 96) {
    // ---------------- KV path (dispatches first, overlaps Q rounds) ----------------
    const int idx = blockIdx.x;  // 0..95
    const int bz = idx / 12;
    const int tm = (idx - bz * 12) * 128;
    const unsigned short* Bb = PB + (long)bz * 98304;
    const int scol = (lane & 7) * 8;

    f32x4 acc[4][4] = {};
    for (int k0 = 0; k0 < 768; k0 += 64) {
      __syncthreads();
#pragma unroll
      for (int i = 0; i < 4; ++i) {
        const int chunk = i * 4 + wave;
        glds16(WKV + (long)(tm + chunk * 8 + srow) * 768 + (k0 + scol), &As[chunk * 512]);
      }
#pragma unroll
      for (int i = 0; i < 4; ++i) {
        const int chunk = i * 4 + wave;
        glds16(Bb + (long)(chunk * 8 + srow) * 768 + (k0 + scol), &Bs[chunk * 512]);
      }
      __syncthreads();
#pragma unroll
      for (int ks = 0; ks < 2; ++ks) {
        bf16x8 af[4], bf[4];
#pragma unroll
        for (int mi = 0; mi < 4; ++mi)
          af[mi] = *reinterpret_cast<const bf16x8*>(&As[(wm + mi * 16 + fr) * 64 + ks * 32 + fk]);
#pragma unroll
        for (int ni = 0; ni < 4; ++ni)
          bf[ni] = *reinterpret_cast<const bf16x8*>(&Bs[(wn + ni * 16 + fr) * 64 + ks * 32 + fk]);
#pragma unroll
        for (int mi = 0; mi < 4; ++mi)
#pragma unroll
          for (int ni = 0; ni < 4; ++ni)
            acc[mi][ni] =
                __builtin_amdgcn_mfma_f32_16x16x32_bf16(af[mi], bf[ni], acc[mi][ni], 0, 0, 0);
      }
    }
#pragma unroll
    for (int mi = 0; mi < 4; ++mi) {
#pragma unroll
      for (int ni = 0; ni < 4; ++ni) {
        const int col = wn + ni * 16 + fr;
        if (col < 77) {
#pragma unroll
          for (int r = 0; r < 4; ++r) {
            const int row = tm + wm + mi * 16 + r0 + r;
            const unsigned short v = f2bf(acc[mi][ni][r] + BKV[row]);
            if (tm < 768) {
              KV[(long)bz * 59136 + (long)row * 77 + col] = v;
            } else {
              const int p = (row - 768) * 77 + col;
              const int snew = p / 768;
              const int c0 = p - snew * 768;
              VT2[(long)bz * 79872 + (long)c0 * 104 + snew] = v;
            }
          }
        }
      }
    }
    return;
  }

  // ---------------- Q path (BK=64) ----------------
  const int bid = blockIdx.x - 96;  // 0..1535; 96%8==0 preserves XCD mapping
  const int l = (bid & 7) * 192 + (bid >> 3);
  const int tm = (l % 6) * 128;
  const int tn = (l / 6) * 128;
  const int srcx = ((lane & 7) ^ srow) * 8;  // pre-swizzled source col
  const int rx = (fr & 7) * 8;               // ds_read XOR

  f32x4 acc[4][4] = {};
  for (int k0 = 0; k0 < 768; k0 += 64) {
    __syncthreads();
#pragma unroll
    for (int i = 0; i < 4; ++i) {
      const int chunk = i * 4 + wave;
      glds16(WQ + (long)(tm + chunk * 8 + srow) * 768 + (k0 + srcx), &As[chunk * 512]);
    }
#pragma unroll
    for (int i = 0; i < 4; ++i) {
      const int chunk = i * 4 + wave;
      glds16(XB + (long)(tn + chunk * 8 + srow) * 768 + (k0 + srcx), &Bs[chunk * 512]);
    }
    __syncthreads();
#pragma unroll
    for (int ks = 0; ks < 2; ++ks) {
      bf16x8 af[4], bf[4];
#pragma unroll
      for (int mi = 0; mi < 4; ++mi)
        af[mi] = *reinterpret_cast<const bf16x8*>(
            &As[(wm + mi * 16 + fr) * 64 + ((ks * 32 + fk) ^ rx)]);
#pragma unroll
      for (int ni = 0; ni < 4; ++ni)
        bf[ni] = *reinterpret_cast<const bf16x8*>(
            &Bs[(wn + ni * 16 + fr) * 64 + ((ks * 32 + fk) ^ rx)]);
#pragma unroll
      for (int mi = 0; mi < 4; ++mi)
#pragma unroll
        for (int ni = 0; ni < 4; ++ni)
          acc[mi][ni] =
              __builtin_amdgcn_mfma_f32_16x16x32_bf16(af[mi], bf[ni], acc[mi][ni], 0, 0, 0);
    }
  }

  // quirk epilogue: bias + cvt_pk into LDS [cm][ct] (stride 136), coalesced stores
  __syncthreads();
#pragma unroll
  for (int mi = 0; mi < 4; ++mi) {
    const int cmb = wm + mi * 16 + r0;
#pragma unroll
    for (int ni = 0; ni < 4; ++ni) {
      const int ct = wn + ni * 16 + fr;
      const unsigned int p01 =
          cvtpk(acc[mi][ni][0] + BQ[tm + cmb], acc[mi][ni][1] + BQ[tm + cmb + 1]);
      const unsigned int p23 =
          cvtpk(acc[mi][ni][2] + BQ[tm + cmb + 2], acc[mi][ni][3] + BQ[tm + cmb + 3]);
      S[(cmb + 0) * 136 + ct] = (unsigned short)p01;
      S[(cmb + 1) * 136 + ct] = (unsigned short)(p01 >> 16);
      S[(cmb + 2) * 136 + ct] = (unsigned short)p23;
      S[(cmb + 3) * 136 + ct] = (unsigned short)(p23 >> 16);
    }
  }
  __syncthreads();
  const int b_ = tn >> 12;
  const int toff = tn & 4095;
  const int cm = tid >> 1;
  const int t8 = (tid & 1) * 64;
  const long gb = (long)b_ * 3145728 + (long)(tm + cm) * 4096 + toff + t8;
#pragma unroll
  for (int j = 0; j < 8; ++j)
    *reinterpret_cast<u16x8*>(&QT[gb + j * 8]) =
        *reinterpret_cast<const u16x8*>(&S[cm * 136 + t8 + j * 8]);
}

// ======== 128x128 out-GEMM (BK=64), XCD-chunked 1D grid + T2 swizzle (f32 out) ========
__global__ __launch_bounds__(256, 4) void k_gout(const unsigned short* __restrict__ A,
                                                 const unsigned short* __restrict__ B,
                                                 float* __restrict__ out,
                                                 const float* __restrict__ bias) {
  __shared__ alignas(16) unsigned short S[16384];
  unsigned short* const As = S;
  unsigned short* const Bs = S + 8192;

  const int tid = threadIdx.x;
  const int wave = tid >> 6;
  const int lane = tid & 63;
  const int l = (blockIdx.x & 7) * 192 + (blockIdx.x >> 3);
  const int tm = (l / 6) * 128;
  const int tn = (l % 6) * 128;
  const int wm = (wave >> 1) * 64;
  const int wn = (wave & 1) * 64;
  const int fr = lane & 15;
  const int fk = (lane >> 4) * 8;
  const int srow = lane >> 3;
  const int srcx = ((lane & 7) ^ srow) * 8;
  const int rx = (fr & 7) * 8;

  f32x4 acc[4][4] = {};

  for (int k0 = 0; k0 < 768; k0 += 64) {
    __syncthreads();
#pragma unroll
    for (int i = 0; i < 4; ++i) {
      const int chunk = i * 4 + wave;
      glds16(A + (long)(tm + chunk * 8 + srow) * 768 + (k0 + srcx), &As[chunk * 512]);
    }
#pragma unroll
    for (int i = 0; i < 4; ++i) {
      const int chunk = i * 4 + wave;
      glds16(B + (long)(tn + chunk * 8 + srow) * 768 + (k0 + srcx), &Bs[chunk * 512]);
    }
    __syncthreads();
#pragma unroll
    for (int ks = 0; ks < 2; ++ks) {
      bf16x8 af[4], bf[4];
#pragma unroll
      for (int mi = 0; mi < 4; ++mi)
        af[mi] = *reinterpret_cast<const bf16x8*>(
            &As[(wm + mi * 16 + fr) * 64 + ((ks * 32 + fk) ^ rx)]);
#pragma unroll
      for (int ni = 0; ni < 4; ++ni)
        bf[ni] = *reinterpret_cast<const bf16x8*>(
            &Bs[(wn + ni * 16 + fr) * 64 + ((ks * 32 + fk) ^ rx)]);
#pragma unroll
      for (int mi = 0; mi < 4; ++mi)
#pragma unroll
        for (int ni = 0; ni < 4; ++ni)
          acc[mi][ni] =
              __builtin_amdgcn_mfma_f32_16x16x32_bf16(af[mi], bf[ni], acc[mi][ni], 0, 0, 0);
    }
  }

  const int r0 = (lane >> 4) * 4;
#pragma unroll
  for (int mi = 0; mi < 4; ++mi) {
#pragma unroll
    for (int ni = 0; ni < 4; ++ni) {
      const int col = tn + wn + ni * 16 + fr;
      const float bv = bias[col];
#pragma unroll
      for (int r = 0; r < 4; ++r) {
        const long g = tm + wm + mi * 16 + r0 + r;
        out[g * 768 + col] = acc[mi][ni][r] + bv;
      }
    }
  }
}

// ---------------- MFMA fused cross-attention (setprio around MFMA clusters) ----------------
__global__ __launch_bounds__(256, 4) void k_attn(const unsigned short* __restrict__ QT,
                                                 const unsigned short* __restrict__ KVT,
                                                 const unsigned short* __restrict__ VT2,
                                                 unsigned short* __restrict__ Y) {
  __shared__ alignas(16) unsigned short Plds[128 * 104];  // P, then O-bounce
  __shared__ alignas(16) unsigned short Vt[64 * 104];

  const int b = blockIdx.z;
  const int h = blockIdx.y;
  const int tid = threadIdx.x;
  const int wave = tid >> 6;
  const int lane = tid & 63;
  const int fr = lane & 15;
  const int fg = lane >> 4;

  const unsigned short* vsrc = VT2 + (long)b * 79872 + h * 6656;
#pragma unroll
  for (int r = 0; r < 4; ++r) {
    const int chunk = r * 256 + tid;
    if (chunk < 832) glds16(vsrc + chunk * 8, &Vt[chunk * 8]);
  }

  {
    const int row = wave * 32 + (lane >> 1);
    u16x8 z = {};
    *reinterpret_cast<u16x8*>(&Plds[row * 104 + 80 + (lane & 1) * 8]) = z;
  }

  const int t0 = blockIdx.x * 128 + wave * 32;
  const long qb = (long)b * 3145728 + h * 64;
  const long kflat = (long)b * 59136 + h * 64;

  bf16x8 qa[2][2];
#pragma unroll
  for (int m = 0; m < 2; ++m)
#pragma unroll
    for (int ks = 0; ks < 2; ++ks)
      qa[m][ks] = *reinterpret_cast<const bf16x8*>(
          &QT[qb + (long)(t0 + m * 16 + fr) * 768 + ks * 32 + fg * 8]);

  bf16x8 kb[5][2];
#pragma unroll
  for (int n = 0; n < 5; ++n)
#pragma unroll
    for (int ks = 0; ks < 2; ++ks)
      kb[n][ks] = *reinterpret_cast<const bf16x8*>(
          &KVT[kflat + (long)(n * 16 + fr) * 768 + ks * 32 + fg * 8]);

  f32x4 s_[2][5] = {};
  __builtin_amdgcn_s_setprio(1);
#pragma unroll
  for (int ks = 0; ks < 2; ++ks)
#pragma unroll
    for (int m = 0; m < 2; ++m)
#pragma unroll
      for (int n = 0; n < 5; ++n)
        s_[m][n] = __builtin_amdgcn_mfma_f32_16x16x32_bf16(qa[m][ks], kb[n][ks], s_[m][n], 0, 0, 0);
  __builtin_amdgcn_s_setprio(0);

  const float scale = 0.036084391824351615f;  // 1/sqrt(768) (quirk: d_prompt)
  f32x4 rl[2];
#pragma unroll
  for (int m = 0; m < 2; ++m) {
#pragma unroll
    for (int n = 0; n < 5; ++n) {
      const int key = n * 16 + fr;
#pragma unroll
      for (int r = 0; r < 4; ++r)
        s_[m][n][r] = (key < 77) ? __expf(s_[m][n][r] * scale) : 0.f;
    }
    f32x4 t = s_[m][0] + s_[m][1] + s_[m][2] + s_[m][3] + s_[m][4];
#pragma unroll
    for (int w = 1; w < 16; w <<= 1) {
      f32x4 u;
#pragma unroll
      for (int r = 0; r < 4; ++r) u[r] = __shfl_xor(t[r], w);
      t += u;
    }
    rl[m][0] = 1.f / t[0]; rl[m][1] = 1.f / t[1];
    rl[m][2] = 1.f / t[2]; rl[m][3] = 1.f / t[3];
  }

#pragma unroll
  for (int m = 0; m < 2; ++m)
#pragma unroll
    for (int n = 0; n < 5; ++n) {
      const unsigned int p01 = cvtpk(s_[m][n][0], s_[m][n][1]);
      const unsigned int p23 = cvtpk(s_[m][n][2], s_[m][n][3]);
      const int base = wave * 32 + m * 16 + fg * 4;
      const int col = n * 16 + fr;
      Plds[(base + 0) * 104 + col] = (unsigned short)p01;
      Plds[(base + 1) * 104 + col] = (unsigned short)(p01 >> 16);
      Plds[(base + 2) * 104 + col] = (unsigned short)p23;
      Plds[(base + 3) * 104 + col] = (unsigned short)(p23 >> 16);
    }

  __syncthreads();  // drains glds16 V-stage + P writes

  f32x4 o[2][4] = {};
  __builtin_amdgcn_s_setprio(1);
#pragma unroll
  for (int ks = 0; ks < 3; ++ks) {
    bf16x8 pa[2], vb[4];
#pragma unroll
    for (int m = 0; m < 2; ++m)
      pa[m] = *reinterpret_cast<const bf16x8*>(
          &Plds[(wave * 32 + m * 16 + fr) * 104 + ks * 32 + fg * 8]);
#pragma unroll
    for (int n = 0; n < 4; ++n)
      vb[n] = *reinterpret_cast<const bf16x8*>(&Vt[(n * 16 + fr) * 104 + ks * 32 + fg * 8]);
#pragma unroll
    for (int m = 0; m < 2; ++m)
#pragma unroll
      for (int n = 0; n < 4; ++n)
        o[m][n] = __builtin_amdgcn_mfma_f32_16x16x32_bf16(pa[m], vb[n], o[m][n], 0, 0, 0);
  }
  __builtin_amdgcn_s_setprio(0);

#pragma unroll
  for (int m = 0; m < 2; ++m)
#pragma unroll
    for (int n = 0; n < 4; ++n) {
      const unsigned int p01 = cvtpk(o[m][n][0] * rl[m][0], o[m][n][1] * rl[m][1]);
      const unsigned int p23 = cvtpk(o[m][n][2] * rl[m][2], o[m][n][3] * rl[m][3]);
      const int base = wave * 32 + m * 16 + fg * 4;
      const int col = n * 16 + fr;
      Plds[(base + 0) * 104 + col] = (unsigned short)p01;
      Plds[(base + 1) * 104 + col] = (unsigned short)(p01 >> 16);
      Plds[(base + 2) * 104 + col] = (unsigned short)p23;
      Plds[(base + 3) * 104 + col] = (unsigned short)(p23 >> 16);
    }
#pragma unroll
  for (int j = 0; j < 4; ++j) {
    const int chunk = j * 64 + lane;
    const int row = chunk >> 3;
    const int d8 = (chunk & 7) * 8;
    *reinterpret_cast<u16x8*>(&Y[qb + (long)(t0 + row) * 768 + d8]) =
        *reinterpret_cast<const u16x8*>(&Plds[(wave * 32 + row) * 104 + d8]);
  }
}

// ---------------- launch ----------------
extern "C" void kernel_launch(void* const* d_in, const int* in_sizes, int n_in,
                              void* d_out, int out_size, void* d_ws, size_t ws_size,
                              hipStream_t stream) {
  const float* x      = (const float*)d_in[0];
  const float* prompt = (const float*)d_in[1];
  const float* Wq     = (const float*)d_in[2];
  const float* bq     = (const float*)d_in[3];
  const float* Wk     = (const float*)d_in[4];
  const float* bk     = (const float*)d_in[5];
  const float* Wv     = (const float*)d_in[6];
  const float* bv     = (const float*)d_in[7];
  const float* Wp     = (const float*)d_in[8];
  const float* bp     = (const float*)d_in[9];
  float* out = (float*)d_out;

  if (ws_size < 109185024u) return;
  char* ws = (char*)d_ws;
  unsigned short* xb   = (unsigned short*)(ws + 0);           // 50,331,648 B
  unsigned short* y    = xb;                                  // alias (xb dead after Q-GEMM)
  unsigned short* qt   = (unsigned short*)(ws + 50331648L);
  unsigned short* wqb  = (unsigned short*)(ws + 100663296L);
  unsigned short* wpb  = (unsigned short*)(ws + 101842944L);
  unsigned short* wkvb = (unsigned short*)(ws + 103022592L);
  unsigned short* pb   = (unsigned short*)(ws + 105381888L);
  unsigned short* kvt  = (unsigned short*)(ws + 106954752L);  // 946,176 B (K only)
  unsigned short* vt2  = (unsigned short*)(ws + 107900928L);  // 1,277,952 B (V^T quirk)
  float*          bkv  = (float*)(ws + 109178880L);           // 6,144 B

  k_prep<<<5438, 256, 0, stream>>>(x, Wq, Wk, Wv, Wp, prompt, bk, bv,
                                   xb, wqb, wkvb, wpb, pb, bkv, vt2);

  // merged: KV projection (96 blocks, FIRST) + Q projection (1536 blocks, BK=64)
  k_qkv<<<1632, 256, 0, stream>>>(wqb, xb, qt, bq, wkvb, pb, kvt, vt2, bkv);

  k_attn<<<dim3(32, 12, 8), 256, 0, stream>>>(qt, kvt, vt2, y);

  // out: A=y flat (32768,768), B=Wp (768,768); f32 out, bias per col
  k_gout<<<1536, 256, 0, stream>>>(y, wpb, out, bp);
}